// Round 1
// baseline (1314.898 us; speedup 1.0000x reference)
//
#include <hip/hip_runtime.h>
#include <hip/hip_bf16.h>

// PQLinearSuper: Y = X @ W^T + b, W reconstructed from PQ codebook.
// M=16384 (8*2048), N=4096 (out), K=4096 (in).
// Strategy: dequant W -> bf16 [N][K] in ws, convert X -> bf16 [M][K] in ws,
// then bf16 MFMA GEMM (m97-style 128x128 tile, global_load_lds staging).

typedef __attribute__((ext_vector_type(4))) float f32x4;
typedef __attribute__((ext_vector_type(8))) short s16x8;

__device__ inline unsigned short f2bf_rne(float f) {
  union { float f; unsigned int u; } v; v.f = f;
  unsigned int u = v.u;
  unsigned int r = u + 0x7fffu + ((u >> 16) & 1u);
  return (unsigned short)(r >> 16);
}

// ---- kernel 1: X fp32 -> bf16 (67,108,864 elements, 8 per thread) ----
__global__ void pq_cvt_x(const float* __restrict__ x, unsigned short* __restrict__ xb) {
  long i = ((long)blockIdx.x * blockDim.x + threadIdx.x) * 8;
  f32x4 a = *(const f32x4*)(x + i);
  f32x4 b = *(const f32x4*)(x + i + 4);
  s16x8 o;
  o[0] = (short)f2bf_rne(a[0]); o[1] = (short)f2bf_rne(a[1]);
  o[2] = (short)f2bf_rne(a[2]); o[3] = (short)f2bf_rne(a[3]);
  o[4] = (short)f2bf_rne(b[0]); o[5] = (short)f2bf_rne(b[1]);
  o[6] = (short)f2bf_rne(b[2]); o[7] = (short)f2bf_rne(b[3]);
  *(s16x8*)(xb + i) = o;
}

// ---- kernel 2: reconstruct W[o][i] bf16 ----
// W[bx*1024+od, by*1024+nb*8+j] = cent[bx,by, asg[bx,by, nb*1024+od], j]
// thread t: o = t>>9 ; q = t&511 -> by = q>>7, nb = q&127  (write-coalesced)
__global__ void pq_recon_w(const float* __restrict__ cent, const int* __restrict__ asg,
                           unsigned short* __restrict__ wb) {
  int t = blockIdx.x * blockDim.x + threadIdx.x;  // 2,097,152 threads
  int o = t >> 9;
  int q = t & 511;
  int by = q >> 7;
  int nb = q & 127;
  int bx = o >> 10;
  int od = o & 1023;
  int pg = (bx << 2) + by;             // centroid/assignment page
  int a = asg[((long)pg << 17) + (nb << 10) + od];
  const float* c = cent + ((long)((pg << 8) + a) << 3);
  f32x4 c0 = *(const f32x4*)c;
  f32x4 c1 = *(const f32x4*)(c + 4);
  s16x8 w;
  w[0] = (short)f2bf_rne(c0[0]); w[1] = (short)f2bf_rne(c0[1]);
  w[2] = (short)f2bf_rne(c0[2]); w[3] = (short)f2bf_rne(c0[3]);
  w[4] = (short)f2bf_rne(c1[0]); w[5] = (short)f2bf_rne(c1[1]);
  w[6] = (short)f2bf_rne(c1[2]); w[7] = (short)f2bf_rne(c1[3]);
  *(s16x8*)(wb + (long)o * 4096 + (by << 10) + (nb << 3)) = w;
}

// ---- kernel 3: bf16 GEMM, C[m][n] = sum_k A[m][k]*B[n][k] + bias[n] ----
__device__ inline void gload_lds16(const unsigned short* g, unsigned short* l) {
  __builtin_amdgcn_global_load_lds(
      (const __attribute__((address_space(1))) void*)g,
      (__attribute__((address_space(3))) void*)l,
      16, 0, 0);
}

__global__ __launch_bounds__(256) void pq_gemm(
    const unsigned short* __restrict__ Ab,   // [16384][4096] bf16
    const unsigned short* __restrict__ Bb,   // [4096][4096] bf16 (W[o][i])
    const float* __restrict__ bias,
    float* __restrict__ C) {                 // [16384][4096] fp32
  __shared__ unsigned short ldsA[128 * 32];
  __shared__ unsigned short ldsB[128 * 32];

  // bijective XCD swizzle: nwg = 4096 = 8 * 512
  int bid = blockIdx.x;
  int wg = (bid & 7) * 512 + (bid >> 3);
  int mt = wg >> 5;          // 128 m-tiles
  int nt = wg & 31;          // 32 n-tiles
  long m0 = (long)mt * 128;
  int n0 = nt * 128;

  int tid = threadIdx.x;
  int w = tid >> 6;          // 4 waves, 2x2 of 64x64
  int lane = tid & 63;
  int wm = w >> 1, wn = w & 1;

  f32x4 acc[4][4];
#pragma unroll
  for (int i = 0; i < 4; ++i)
#pragma unroll
    for (int j = 0; j < 4; ++j)
      acc[i][j] = (f32x4){0.f, 0.f, 0.f, 0.f};

  // staging: wave w covers rows [w*32, w*32+32) of each tile, 2 issues of 16 rows
  int rowbase = w * 32;
  int srow = lane >> 2;          // 16 rows per issue, 4 lanes per 64B row
  int scol = (lane & 3) * 8;     // bf16 elements (16B per lane)
  const unsigned short* gA0 = Ab + (m0 + rowbase + srow) * 4096 + scol;
  const unsigned short* gB0 = Bb + (long)(n0 + rowbase + srow) * 4096 + scol;
  unsigned short* lA0 = &ldsA[rowbase * 32];
  unsigned short* lA1 = &ldsA[(rowbase + 16) * 32];
  unsigned short* lB0 = &ldsB[rowbase * 32];
  unsigned short* lB1 = &ldsB[(rowbase + 16) * 32];
  const long g16 = 16L * 4096;

  // fragment read offsets (bf16 elements): lane holds row (lane&15), k-half (lane>>4)*8
  int fr = lane & 15;
  int fk = (lane >> 4) * 8;
  int aoff = (wm * 64 + fr) * 32 + fk;
  int boff = (wn * 64 + fr) * 32 + fk;

  for (int kt = 0; kt < 4096; kt += 32) {
    gload_lds16(gA0 + kt, lA0);
    gload_lds16(gA0 + g16 + kt, lA1);
    gload_lds16(gB0 + kt, lB0);
    gload_lds16(gB0 + g16 + kt, lB1);
    __syncthreads();             // drains vmcnt -> LDS tiles ready
    s16x8 af[4], bfr[4];
#pragma unroll
    for (int mf = 0; mf < 4; ++mf) af[mf] = *(const s16x8*)&ldsA[aoff + mf * 512];
#pragma unroll
    for (int nf = 0; nf < 4; ++nf) bfr[nf] = *(const s16x8*)&ldsB[boff + nf * 512];
#pragma unroll
    for (int mf = 0; mf < 4; ++mf)
#pragma unroll
      for (int nf = 0; nf < 4; ++nf)
        acc[mf][nf] = __builtin_amdgcn_mfma_f32_16x16x32_bf16(af[mf], bfr[nf], acc[mf][nf], 0, 0, 0);
    __syncthreads();             // protect LDS before next stage
  }

  // epilogue: C/D layout col=lane&15, row=(lane>>4)*4+reg (m89/m91-verified)
  int col = lane & 15;
  int r0 = (lane >> 4) * 4;
#pragma unroll
  for (int mf = 0; mf < 4; ++mf) {
#pragma unroll
    for (int nf = 0; nf < 4; ++nf) {
      long gm = m0 + wm * 64 + mf * 16 + r0;
      int gn = n0 + wn * 64 + nf * 16 + col;
      float bv = bias[gn];
#pragma unroll
      for (int rr = 0; rr < 4; ++rr)
        C[(gm + rr) * 4096 + gn] = acc[mf][nf][rr] + bv;
    }
  }
}

extern "C" void kernel_launch(void* const* d_in, const int* in_sizes, int n_in,
                              void* d_out, int out_size, void* d_ws, size_t ws_size,
                              hipStream_t stream) {
  const float* x    = (const float*)d_in[0];  // (8,2048,4096) f32
  const float* cent = (const float*)d_in[1];  // (4,4,256,8) f32
  const float* bias = (const float*)d_in[2];  // (4096,) f32
  const int*   asg  = (const int*)d_in[3];    // (4,4,131072) i32
  float* out = (float*)d_out;                 // (8,2048,4096) f32

  unsigned short* xb = (unsigned short*)d_ws;                          // 134,217,728 B
  unsigned short* wb = (unsigned short*)((char*)d_ws + 134217728ULL);  // +33,554,432 B

  pq_cvt_x<<<32768, 256, 0, stream>>>(x, xb);
  pq_recon_w<<<8192, 256, 0, stream>>>(cent, asg, wb);
  pq_gemm<<<4096, 256, 0, stream>>>(xb, wb, bias, out);
}

// Round 2
// 970.336 us; speedup vs baseline: 1.3551x; 1.3551x over previous
//
#include <hip/hip_runtime.h>
#include <hip/hip_bf16.h>

// PQLinearSuper: Y = X @ W^T + b.  M=16384, N=4096, K=4096.
// R2: 256x256 tile, BK=32, 4-deep LDS ring, counted vmcnt(12) (T4),
// both-sides XOR swizzle (T2), raw s_barrier (no drain-0).

typedef __attribute__((ext_vector_type(4))) float f32x4;
typedef __attribute__((ext_vector_type(8))) short s16x8;

__device__ inline unsigned short f2bf_rne(float f) {
  union { float f; unsigned int u; } v; v.f = f;
  unsigned int u = v.u;
  unsigned int r = u + 0x7fffu + ((u >> 16) & 1u);
  return (unsigned short)(r >> 16);
}

// ---- kernel 1: X fp32 -> bf16 ----
__global__ void pq_cvt_x(const float* __restrict__ x, unsigned short* __restrict__ xb) {
  long i = ((long)blockIdx.x * blockDim.x + threadIdx.x) * 8;
  f32x4 a = *(const f32x4*)(x + i);
  f32x4 b = *(const f32x4*)(x + i + 4);
  s16x8 o;
  o[0] = (short)f2bf_rne(a[0]); o[1] = (short)f2bf_rne(a[1]);
  o[2] = (short)f2bf_rne(a[2]); o[3] = (short)f2bf_rne(a[3]);
  o[4] = (short)f2bf_rne(b[0]); o[5] = (short)f2bf_rne(b[1]);
  o[6] = (short)f2bf_rne(b[2]); o[7] = (short)f2bf_rne(b[3]);
  *(s16x8*)(xb + i) = o;
}

// ---- kernel 2: reconstruct W[o][i] bf16 ----
__global__ void pq_recon_w(const float* __restrict__ cent, const int* __restrict__ asg,
                           unsigned short* __restrict__ wb) {
  int t = blockIdx.x * blockDim.x + threadIdx.x;
  int o = t >> 9;
  int q = t & 511;
  int by = q >> 7;
  int nb = q & 127;
  int bx = o >> 10;
  int od = o & 1023;
  int pg = (bx << 2) + by;
  int a = asg[((long)pg << 17) + (nb << 10) + od];
  const float* c = cent + ((long)((pg << 8) + a) << 3);
  f32x4 c0 = *(const f32x4*)c;
  f32x4 c1 = *(const f32x4*)(c + 4);
  s16x8 w;
  w[0] = (short)f2bf_rne(c0[0]); w[1] = (short)f2bf_rne(c0[1]);
  w[2] = (short)f2bf_rne(c0[2]); w[3] = (short)f2bf_rne(c0[3]);
  w[4] = (short)f2bf_rne(c1[0]); w[5] = (short)f2bf_rne(c1[1]);
  w[6] = (short)f2bf_rne(c1[2]); w[7] = (short)f2bf_rne(c1[3]);
  *(s16x8*)(wb + (long)o * 4096 + (by << 10) + (nb << 3)) = w;
}

// ---- kernel 3: 256x256 GEMM, ring-4 counted-vmcnt pipeline ----
__device__ inline void gl16(const unsigned short* g, const char* l) {
  __builtin_amdgcn_global_load_lds(
      (const __attribute__((address_space(1))) void*)g,
      (__attribute__((address_space(3))) void*)l, 16, 0, 0);
}

__global__ __launch_bounds__(512, 2) void pq_gemm(
    const unsigned short* __restrict__ Ab,   // [16384][4096] bf16
    const unsigned short* __restrict__ Bb,   // [4096][4096] bf16
    const float* __restrict__ bias,
    float* __restrict__ C) {                 // [16384][4096] f32
  // 4 ring slots x (A 256x32 + B 256x32) bf16 = 4 x 32 KiB = 128 KiB
  __shared__ unsigned short lds[65536];

  // XCD swizzle: nwg = 1024 = 8 * 128 (bijective)
  int bid = blockIdx.x;
  int wg = (bid & 7) * 128 + (bid >> 3);
  int mt = wg >> 4;           // 64 m-tiles
  int nt = wg & 15;           // 16 n-tiles
  long m0 = (long)mt * 256;
  int n0 = nt * 256;

  int tid = threadIdx.x;
  int w = tid >> 6, lane = tid & 63;
  int wm = w >> 2, wn = w & 3;     // 2 x 4 waves, per-wave 128x64 output

  // ---- staging addresses (pre-swizzled global source, linear LDS dest) ----
  // dest row r = tid>>2, physical 16B-slot p = tid&3; source col = 8*(p ^ ((r>>1)&3))
  int sr = tid >> 2;
  int scol = (((tid & 3) ^ ((tid >> 3) & 3)) << 3);
  const unsigned short* a0 = Ab + (m0 + sr) * 4096 + scol;
  const unsigned short* a1 = a0 + 128 * 4096;
  const unsigned short* b0 = Bb + (long)(n0 + sr) * 4096 + scol;
  const unsigned short* b1 = b0 + 128 * 4096;
  char* lc = (char*)lds;
  int oA0 = w * 1024, oA1 = 8192 + w * 1024;
  int oB0 = 16384 + w * 1024, oB1 = 24576 + w * 1024;

#define STAGE(T) { int sb_ = ((T) & 3) << 15; int kt_ = (T) << 5; \
    gl16(a0 + kt_, lc + sb_ + oA0); \
    gl16(a1 + kt_, lc + sb_ + oA1); \
    gl16(b0 + kt_, lc + sb_ + oB0); \
    gl16(b1 + kt_, lc + sb_ + oB1); }

  // ---- fragment read offsets (swizzled): slot = h ^ ((row>>1)&3) ----
  int fr = lane & 15, h = lane >> 4;
  int xs = ((h ^ ((fr >> 1) & 3)) << 3);
  int aoff = (wm * 128 + fr) * 32 + xs;          // + mf*512 + slot*16384
  int boff = 8192 + (wn * 64 + fr) * 32 + xs;    // + nf*512 + slot*16384

  f32x4 acc[8][4];
#pragma unroll
  for (int i = 0; i < 8; ++i)
#pragma unroll
    for (int j = 0; j < 4; ++j)
      acc[i][j] = (f32x4){0.f, 0.f, 0.f, 0.f};

#define BODY(T) { int se_ = ((T) & 3) << 14; \
    s16x8 af[8]; s16x8 bf[4]; \
    _Pragma("unroll") for (int mf = 0; mf < 8; ++mf) \
      af[mf] = *(const s16x8*)&lds[se_ + aoff + mf * 512]; \
    _Pragma("unroll") for (int nf = 0; nf < 4; ++nf) \
      bf[nf] = *(const s16x8*)&lds[se_ + boff + nf * 512]; \
    _Pragma("unroll") for (int mf = 0; mf < 8; ++mf) \
      _Pragma("unroll") for (int nf = 0; nf < 4; ++nf) \
        acc[mf][nf] = __builtin_amdgcn_mfma_f32_16x16x32_bf16(af[mf], bf[nf], acc[mf][nf], 0, 0, 0); }

  // counted-vmcnt K-step: wait leaves {t+1,t+2,t+3} (12 loads) in flight,
  // proving tile t arrived; barrier-2 protects slot reuse (write-after-read).
#define KSTEP(T, CNT) \
    asm volatile("s_waitcnt vmcnt(" CNT ")" ::: "memory"); \
    __builtin_amdgcn_s_barrier(); \
    __builtin_amdgcn_sched_barrier(0); \
    BODY(T); \
    __builtin_amdgcn_sched_barrier(0); \
    __builtin_amdgcn_s_barrier();

  STAGE(0); STAGE(1); STAGE(2);

  for (int t = 0; t < 125; ++t) {
    STAGE(t + 3);
    KSTEP(t, "12");
  }
  KSTEP(125, "8");
  KSTEP(126, "4");
  KSTEP(127, "0");

#undef STAGE
#undef BODY
#undef KSTEP

  // ---- epilogue: C/D layout col=lane&15, row=(lane>>4)*4+reg ----
  int col = lane & 15, r0 = h * 4;
  long mbase = m0 + wm * 128;
  int nbase = n0 + wn * 64;
#pragma unroll
  for (int nf = 0; nf < 4; ++nf) {
    int gn = nbase + nf * 16 + col;
    float bv = bias[gn];
#pragma unroll
    for (int mf = 0; mf < 8; ++mf) {
      long gm = mbase + mf * 16 + r0;
#pragma unroll
      for (int rr = 0; rr < 4; ++rr)
        C[(gm + rr) * 4096 + gn] = acc[mf][nf][rr] + bv;
    }
  }
}

extern "C" void kernel_launch(void* const* d_in, const int* in_sizes, int n_in,
                              void* d_out, int out_size, void* d_ws, size_t ws_size,
                              hipStream_t stream) {
  const float* x    = (const float*)d_in[0];
  const float* cent = (const float*)d_in[1];
  const float* bias = (const float*)d_in[2];
  const int*   asg  = (const int*)d_in[3];
  float* out = (float*)d_out;

  unsigned short* xb = (unsigned short*)d_ws;                          // 128 MiB
  unsigned short* wb = (unsigned short*)((char*)d_ws + 134217728ULL);  // +32 MiB

  pq_cvt_x<<<32768, 256, 0, stream>>>(x, xb);
  pq_recon_w<<<8192, 256, 0, stream>>>(cent, asg, wb);
  pq_gemm<<<1024, 512, 0, stream>>>(xb, wb, bias, out);
}